// Round 1
// baseline (370.466 us; speedup 1.0000x reference)
//
#include <hip/hip_runtime.h>
#include <hip/hip_bf16.h>

// PinSageConv on MI355X.
// Algorithmic restructure: precompute q[v] = relu(h[v] @ Q_w.T + Q_b) for ALL
// 100k nodes once (13.1 GFLOP) instead of per-neighbor (131 GFLOP) — neighbors
// are 1M draws from 100k nodes, ~10x duplication, and relu(Qh) depends only on v.
// Workspace layout (needs 61,440,000 B):
//   q_bf16   [100000][256] ushort at offset 0            (51,200,000 B)
//   agg_bf16 [ 20000][256] ushort at offset 51,200,000   (10,240,000 B)

#define M_TOTAL 100000
#define N_NODES 20000
#define T_NB    50
#define IN_F    256
#define HID_F   256
#define OUT_F   256
#define KCAT    512   // IN_F + HID_F

typedef __bf16 bf16x8 __attribute__((ext_vector_type(8)));
typedef float  floatx4 __attribute__((ext_vector_type(4)));

__device__ __forceinline__ unsigned short f2bf(float f) {
    unsigned int u = __float_as_uint(f);
    u += 0x7fffu + ((u >> 16) & 1u);          // round-to-nearest-even
    return (unsigned short)(u >> 16);
}
__device__ __forceinline__ float bf2f(unsigned short s) {
    return __uint_as_float(((unsigned int)s) << 16);
}

// ---------------------------------------------------------------------------
// Kernel 1: q[v,o] = relu(sum_k h[v,k] * Qw[o,k] + Qb[o]),  M=100000 N=256 K=256
// 128x128 tile, 4 waves, each wave 64x64 via 4x4 MFMA 16x16x32 bf16.
// ---------------------------------------------------------------------------
__global__ __launch_bounds__(256)
void qgemm(const float* __restrict__ h, const float* __restrict__ Qw,
           const float* __restrict__ Qb, unsigned short* __restrict__ q) {
    __shared__ unsigned short ldsA[128 * 72];   // +8 pad: 2-way bank pattern (free)
    __shared__ unsigned short ldsB[128 * 72];

    const int tid  = threadIdx.x;
    const int row0 = blockIdx.x * 128;
    const int n0   = blockIdx.y * 128;
    const int lane = tid & 63;
    const int wv   = tid >> 6;
    const int wr   = (wv >> 1) << 6;
    const int wc   = (wv & 1) << 6;
    const int fr   = lane & 15;          // fragment row (m or n) within 16
    const int fk   = (lane >> 4) << 3;   // k offset within 32

    floatx4 acc[4][4];
#pragma unroll
    for (int i = 0; i < 4; ++i)
#pragma unroll
        for (int j = 0; j < 4; ++j)
            acc[i][j] = (floatx4){0.f, 0.f, 0.f, 0.f};

    for (int kb = 0; kb < 4; ++kb) {     // K = 256, BK = 64
        if (kb) __syncthreads();
#pragma unroll
        for (int i = 0; i < 8; ++i) {
            const int e = (i * 256 + tid) * 4;   // flat elem in 128x64 tile
            const int r = e >> 6;
            const int c = e & 63;
            // A tile (h rows, guarded)
            float4 v = make_float4(0.f, 0.f, 0.f, 0.f);
            const int gr = row0 + r;
            if (gr < M_TOTAL)
                v = *(const float4*)(h + (size_t)gr * IN_F + kb * 64 + c);
            ushort4 s;
            s.x = f2bf(v.x); s.y = f2bf(v.y); s.z = f2bf(v.z); s.w = f2bf(v.w);
            *(ushort4*)(&ldsA[r * 72 + c]) = s;
            // B tile (Qw rows, n0+r < 256 always)
            const float4 w = *(const float4*)(Qw + (size_t)(n0 + r) * IN_F + kb * 64 + c);
            ushort4 t;
            t.x = f2bf(w.x); t.y = f2bf(w.y); t.z = f2bf(w.z); t.w = f2bf(w.w);
            *(ushort4*)(&ldsB[r * 72 + c]) = t;
        }
        __syncthreads();
#pragma unroll
        for (int ks = 0; ks < 2; ++ks) {
            bf16x8 av[4], bv[4];
#pragma unroll
            for (int mt = 0; mt < 4; ++mt)
                av[mt] = *reinterpret_cast<const bf16x8*>(&ldsA[(wr + mt * 16 + fr) * 72 + ks * 32 + fk]);
#pragma unroll
            for (int nt = 0; nt < 4; ++nt)
                bv[nt] = *reinterpret_cast<const bf16x8*>(&ldsB[(wc + nt * 16 + fr) * 72 + ks * 32 + fk]);
#pragma unroll
            for (int mt = 0; mt < 4; ++mt)
#pragma unroll
                for (int nt = 0; nt < 4; ++nt)
                    acc[mt][nt] = __builtin_amdgcn_mfma_f32_16x16x32_bf16(av[mt], bv[nt], acc[mt][nt], 0, 0, 0);
        }
    }

    // epilogue: D row = (lane>>4)*4 + r, col = lane&15 (measured m89/m91 layout)
    const int erow = (lane >> 4) << 2;
    const int ecol = lane & 15;
#pragma unroll
    for (int nt = 0; nt < 4; ++nt) {
        const int gcol = n0 + wc + nt * 16 + ecol;
        const float bias = Qb[gcol];
#pragma unroll
        for (int mt = 0; mt < 4; ++mt) {
            const int growb = row0 + wr + mt * 16 + erow;
#pragma unroll
            for (int r = 0; r < 4; ++r) {
                const int gr = growb + r;
                if (gr < M_TOTAL) {
                    float v = acc[mt][nt][r] + bias;
                    q[(size_t)gr * HID_F + gcol] = f2bf(v > 0.f ? v : 0.f);
                }
            }
        }
    }
}

// ---------------------------------------------------------------------------
// Kernel 2: agg[n,f] = (sum_t w[n,t] * q[nb[n,t],f]) / sum_t w[n,t]
// One wave per node, lane handles 4 features (ushort4 = 8B/lane gather).
// ---------------------------------------------------------------------------
__global__ __launch_bounds__(256)
void aggk(const unsigned short* __restrict__ q, const int* __restrict__ nb,
          const float* __restrict__ w, unsigned short* __restrict__ agg) {
    const int node = blockIdx.x * 4 + (threadIdx.x >> 6);
    const int lane = threadIdx.x & 63;
    const int* __restrict__ nbp = nb + (size_t)node * T_NB;
    const float* __restrict__ wp = w + (size_t)node * T_NB;

    float a0 = 0.f, a1 = 0.f, a2 = 0.f, a3 = 0.f, sw = 0.f;
#pragma unroll 5
    for (int t = 0; t < T_NB; ++t) {
        const int idx = nbp[t];
        const float wt = wp[t];
        const ushort4 qv = *(const ushort4*)(q + (size_t)idx * HID_F + lane * 4);
        a0 += wt * bf2f(qv.x);
        a1 += wt * bf2f(qv.y);
        a2 += wt * bf2f(qv.z);
        a3 += wt * bf2f(qv.w);
        sw += wt;
    }
    const float inv = 1.0f / sw;
    ushort4 o;
    o.x = f2bf(a0 * inv); o.y = f2bf(a1 * inv);
    o.z = f2bf(a2 * inv); o.w = f2bf(a3 * inv);
    *(ushort4*)(agg + (size_t)node * HID_F + lane * 4) = o;
}

// ---------------------------------------------------------------------------
// Kernel 3: out[n,o] = relu(sum_k concat(h[nodeset[n]], agg[n])[k] * Ww[o,k] + Wb[o])
// M=20000 N=256 K=512. A staged via gather (k<256: h[nodeset], else agg bf16).
// ---------------------------------------------------------------------------
__global__ __launch_bounds__(256)
void fgemm(const float* __restrict__ h, const int* __restrict__ nodeset,
           const unsigned short* __restrict__ agg,
           const float* __restrict__ Ww, const float* __restrict__ Wb,
           float* __restrict__ out) {
    __shared__ unsigned short ldsA[128 * 72];
    __shared__ unsigned short ldsB[128 * 72];

    const int tid  = threadIdx.x;
    const int row0 = blockIdx.x * 128;
    const int n0   = blockIdx.y * 128;
    const int lane = tid & 63;
    const int wv   = tid >> 6;
    const int wr   = (wv >> 1) << 6;
    const int wc   = (wv & 1) << 6;
    const int fr   = lane & 15;
    const int fk   = (lane >> 4) << 3;

    floatx4 acc[4][4];
#pragma unroll
    for (int i = 0; i < 4; ++i)
#pragma unroll
        for (int j = 0; j < 4; ++j)
            acc[i][j] = (floatx4){0.f, 0.f, 0.f, 0.f};

    for (int kb = 0; kb < 8; ++kb) {     // K = 512, BK = 64
        if (kb) __syncthreads();
#pragma unroll
        for (int i = 0; i < 8; ++i) {
            const int e = (i * 256 + tid) * 4;
            const int r = e >> 6;
            const int c = e & 63;
            const int gr = row0 + r;
            ushort4 s = {0, 0, 0, 0};
            if (gr < N_NODES) {
                if (kb < 4) {            // self features: gather from h
                    const int src = nodeset[gr];
                    const float4 v = *(const float4*)(h + (size_t)src * IN_F + kb * 64 + c);
                    s.x = f2bf(v.x); s.y = f2bf(v.y); s.z = f2bf(v.z); s.w = f2bf(v.w);
                } else {                 // aggregated features: already bf16
                    s = *(const ushort4*)(agg + (size_t)gr * HID_F + (kb - 4) * 64 + c);
                }
            }
            *(ushort4*)(&ldsA[r * 72 + c]) = s;
            const float4 w = *(const float4*)(Ww + (size_t)(n0 + r) * KCAT + kb * 64 + c);
            ushort4 t;
            t.x = f2bf(w.x); t.y = f2bf(w.y); t.z = f2bf(w.z); t.w = f2bf(w.w);
            *(ushort4*)(&ldsB[r * 72 + c]) = t;
        }
        __syncthreads();
#pragma unroll
        for (int ks = 0; ks < 2; ++ks) {
            bf16x8 av[4], bv[4];
#pragma unroll
            for (int mt = 0; mt < 4; ++mt)
                av[mt] = *reinterpret_cast<const bf16x8*>(&ldsA[(wr + mt * 16 + fr) * 72 + ks * 32 + fk]);
#pragma unroll
            for (int nt = 0; nt < 4; ++nt)
                bv[nt] = *reinterpret_cast<const bf16x8*>(&ldsB[(wc + nt * 16 + fr) * 72 + ks * 32 + fk]);
#pragma unroll
            for (int mt = 0; mt < 4; ++mt)
#pragma unroll
                for (int nt = 0; nt < 4; ++nt)
                    acc[mt][nt] = __builtin_amdgcn_mfma_f32_16x16x32_bf16(av[mt], bv[nt], acc[mt][nt], 0, 0, 0);
        }
    }

    const int erow = (lane >> 4) << 2;
    const int ecol = lane & 15;
#pragma unroll
    for (int nt = 0; nt < 4; ++nt) {
        const int gcol = n0 + wc + nt * 16 + ecol;
        const float bias = Wb[gcol];
#pragma unroll
        for (int mt = 0; mt < 4; ++mt) {
            const int growb = row0 + wr + mt * 16 + erow;
#pragma unroll
            for (int r = 0; r < 4; ++r) {
                const int gr = growb + r;
                if (gr < N_NODES) {
                    const float v = acc[mt][nt][r] + bias;
                    out[(size_t)gr * OUT_F + gcol] = (v > 0.f ? v : 0.f);
                }
            }
        }
    }
}

// ---------------------------------------------------------------------------
// Kernel 4: in-place row L2 normalize of out [20000, 256]. One wave per row.
// ---------------------------------------------------------------------------
__global__ __launch_bounds__(256)
void normk(float* __restrict__ out) {
    const int row = blockIdx.x * 4 + (threadIdx.x >> 6);
    const int lane = threadIdx.x & 63;
    float4 v = *(float4*)(out + (size_t)row * OUT_F + lane * 4);
    float ss = v.x * v.x + v.y * v.y + v.z * v.z + v.w * v.w;
#pragma unroll
    for (int off = 32; off > 0; off >>= 1)
        ss += __shfl_xor(ss, off, 64);
    const float s = rsqrtf(ss);
    v.x *= s; v.y *= s; v.z *= s; v.w *= s;
    *(float4*)(out + (size_t)row * OUT_F + lane * 4) = v;
}

extern "C" void kernel_launch(void* const* d_in, const int* in_sizes, int n_in,
                              void* d_out, int out_size, void* d_ws, size_t ws_size,
                              hipStream_t stream) {
    const float* h        = (const float*)d_in[0];
    const int*   nodeset  = (const int*)d_in[1];
    const int*   nb_nodes = (const int*)d_in[2];
    const float* nb_w     = (const float*)d_in[3];
    const float* Qw       = (const float*)d_in[4];
    const float* Qb       = (const float*)d_in[5];
    const float* Ww       = (const float*)d_in[6];
    const float* Wb       = (const float*)d_in[7];
    float* out = (float*)d_out;

    unsigned short* q   = (unsigned short*)d_ws;                     // 100000*256 bf16
    unsigned short* agg = q + (size_t)M_TOTAL * HID_F;               //  20000*256 bf16

    qgemm<<<dim3((M_TOTAL + 127) / 128, 2), 256, 0, stream>>>(h, Qw, Qb, q);
    aggk <<<dim3(N_NODES / 4),            256, 0, stream>>>(q, nb_nodes, nb_w, agg);
    fgemm<<<dim3((N_NODES + 127) / 128, 2), 256, 0, stream>>>(h, nodeset, agg, Ww, Wb, out);
    normk<<<dim3(N_NODES / 4),            256, 0, stream>>>(out);
}

// Round 2
// 312.220 us; speedup vs baseline: 1.1866x; 1.1866x over previous
//
#include <hip/hip_runtime.h>
#include <hip/hip_bf16.h>

// PinSageConv on MI355X — round 2.
// q[v] = relu(h[v] @ Q_w.T + Q_b) precomputed for all 100k nodes (10x FLOP cut
// vs per-neighbor). qgemm v2: async global_load_lds fp32 staging + XOR-swizzled
// LDS + convert-at-fragment-read + LDS-staged coalesced epilogue.
// Workspace: q_bf16 [100000][256] @0 (51.2 MB), agg_bf16 [20000][256] @51.2 MB.

#define M_TOTAL 100000
#define N_NODES 20000
#define T_NB    50
#define IN_F    256
#define HID_F   256
#define OUT_F   256
#define KCAT    512

typedef __bf16 bf16x8 __attribute__((ext_vector_type(8)));
typedef float  floatx4 __attribute__((ext_vector_type(4)));
typedef unsigned short ushortx8 __attribute__((ext_vector_type(8)));

__device__ __forceinline__ unsigned short f2bf(float f) {
    unsigned int u = __float_as_uint(f);
    u += 0x7fffu + ((u >> 16) & 1u);          // RTNE
    return (unsigned short)(u >> 16);
}
__device__ __forceinline__ float bf2f(unsigned short s) {
    return __uint_as_float(((unsigned int)s) << 16);
}
__device__ __forceinline__ void gload16(const void* g, void* l) {
    __builtin_amdgcn_global_load_lds(
        (const __attribute__((address_space(1))) unsigned int*)g,
        (__attribute__((address_space(3))) unsigned int*)l, 16, 0, 0);
}
__device__ __forceinline__ bf16x8 cvt_frag(float4 a, float4 b) {
    bf16x8 r;
    r[0] = (__bf16)a.x; r[1] = (__bf16)a.y; r[2] = (__bf16)a.z; r[3] = (__bf16)a.w;
    r[4] = (__bf16)b.x; r[5] = (__bf16)b.y; r[6] = (__bf16)b.z; r[7] = (__bf16)b.w;
    return r;
}

// ---------------------------------------------------------------------------
// Kernel 1: q = relu(h @ Qw.T + Qb).  M=100000 N=256 K=256.
// 128x128 tile, BK=32, async fp32 staging, swizzled un-padded LDS.
// LDS chunk(row, cl) holds global 16B-chunk cg = cl ^ (row&7) of the k-block.
// ---------------------------------------------------------------------------
__global__ __launch_bounds__(256)
void qgemm(const float* __restrict__ h, const float* __restrict__ Qw,
           const float* __restrict__ Qb, unsigned short* __restrict__ q) {
    __shared__ char smem[32768];                    // A fp32 16K | B fp32 16K; epilogue: C bf16 32K
    float* ldsA = (float*)smem;
    float* ldsB = (float*)(smem + 16384);
    unsigned short* ldsC = (unsigned short*)smem;

    const int tid  = threadIdx.x;
    const int row0 = blockIdx.x * 128;
    const int n0   = blockIdx.y * 128;
    const int lane = tid & 63;
    const int wv   = tid >> 6;
    const int wr   = (wv >> 1) << 6;
    const int wc   = (wv & 1) << 6;
    const int fr   = lane & 15;
    const int fk   = (lane >> 4) << 3;     // k offset within 32: {0,8,16,24}
    const int c0   = fk >> 2;              // logical chunk: {0,2,4,6}

    floatx4 acc[4][4];
#pragma unroll
    for (int i = 0; i < 4; ++i)
#pragma unroll
        for (int j = 0; j < 4; ++j)
            acc[i][j] = (floatx4){0.f, 0.f, 0.f, 0.f};

    for (int kb = 0; kb < 8; ++kb) {       // K = 256, BK = 32
        if (kb) __syncthreads();
        const int k0 = kb * 32;
#pragma unroll
        for (int i = 0; i < 4; ++i) {      // 1024 chunks each for A and B
            const int L   = tid + i * 256;
            const int row = L >> 3;
            const int cg  = (L & 7) ^ (row & 7);
            const int gr  = min(row0 + row, M_TOTAL - 1);
            gload16(h  + (size_t)gr * IN_F + k0 + cg * 4,         smem + L * 16);
            gload16(Qw + (size_t)(n0 + row) * IN_F + k0 + cg * 4, smem + 16384 + L * 16);
        }
        __syncthreads();                   // drains vmcnt(0) for global_load_lds

        bf16x8 av[4], bv[4];
#pragma unroll
        for (int mt = 0; mt < 4; ++mt) {
            const int row = wr + mt * 16 + fr;
            const int sw  = row & 7;
            const float4 p0 = *(const float4*)(ldsA + (row * 8 + (c0 ^ sw)) * 4);
            const float4 p1 = *(const float4*)(ldsA + (row * 8 + ((c0 + 1) ^ sw)) * 4);
            av[mt] = cvt_frag(p0, p1);
        }
#pragma unroll
        for (int nt = 0; nt < 4; ++nt) {
            const int row = wc + nt * 16 + fr;
            const int sw  = row & 7;
            const float4 p0 = *(const float4*)(ldsB + (row * 8 + (c0 ^ sw)) * 4);
            const float4 p1 = *(const float4*)(ldsB + (row * 8 + ((c0 + 1) ^ sw)) * 4);
            bv[nt] = cvt_frag(p0, p1);
        }
#pragma unroll
        for (int mt = 0; mt < 4; ++mt)
#pragma unroll
            for (int nt = 0; nt < 4; ++nt)
                acc[mt][nt] = __builtin_amdgcn_mfma_f32_16x16x32_bf16(av[mt], bv[nt], acc[mt][nt], 0, 0, 0);
    }

    // Epilogue: bias+relu -> bf16 tile in LDS -> coalesced 16B stores.
    __syncthreads();
    const int erow = (lane >> 4) << 2;
    const int ecol = lane & 15;
#pragma unroll
    for (int nt = 0; nt < 4; ++nt) {
        const int cl   = wc + nt * 16 + ecol;
        const float bias = Qb[n0 + cl];
#pragma unroll
        for (int mt = 0; mt < 4; ++mt)
#pragma unroll
            for (int r = 0; r < 4; ++r) {
                const int rl = wr + mt * 16 + erow + r;
                const float v = acc[mt][nt][r] + bias;
                ldsC[rl * 128 + cl] = f2bf(v > 0.f ? v : 0.f);
            }
    }
    __syncthreads();
#pragma unroll
    for (int i = 0; i < 8; ++i) {          // 2048 16B chunks
        const int L   = tid + i * 256;
        const int row = L >> 4;
        const int c   = L & 15;
        const int gr  = row0 + row;
        if (gr < M_TOTAL)
            *(ushortx8*)(q + (size_t)gr * HID_F + n0 + c * 8) =
                *(const ushortx8*)(ldsC + row * 128 + c * 8);
    }
}

// ---------------------------------------------------------------------------
// Kernel 2: agg[n] = sum_t w[n,t]*q[nb[n,t]] / sum_t w[n,t].  One wave/node.
// Lane-parallel neighbor metadata load + shfl broadcast; 50 gathers in flight.
// ---------------------------------------------------------------------------
__global__ __launch_bounds__(256)
void aggk(const unsigned short* __restrict__ q, const int* __restrict__ nb,
          const float* __restrict__ w, unsigned short* __restrict__ agg) {
    const int node = blockIdx.x * 4 + (threadIdx.x >> 6);
    const int lane = threadIdx.x & 63;

    int   idx_l = 0;
    float w_l   = 0.f;
    if (lane < T_NB) {
        idx_l = nb[(size_t)node * T_NB + lane];
        w_l   = w[(size_t)node * T_NB + lane];
    }
    float sw = w_l;
#pragma unroll
    for (int off = 32; off > 0; off >>= 1)
        sw += __shfl_xor(sw, off, 64);

    float a0 = 0.f, a1 = 0.f, a2 = 0.f, a3 = 0.f;
#pragma unroll
    for (int t = 0; t < T_NB; ++t) {
        const int   idx = __shfl(idx_l, t, 64);
        const float wt  = __shfl(w_l, t, 64);
        const ushort4 qv = *(const ushort4*)(q + (size_t)idx * HID_F + lane * 4);
        a0 += wt * bf2f(qv.x);
        a1 += wt * bf2f(qv.y);
        a2 += wt * bf2f(qv.z);
        a3 += wt * bf2f(qv.w);
    }
    const float inv = 1.0f / sw;
    ushort4 o;
    o.x = f2bf(a0 * inv); o.y = f2bf(a1 * inv);
    o.z = f2bf(a2 * inv); o.w = f2bf(a3 * inv);
    *(ushort4*)(agg + (size_t)node * HID_F + lane * 4) = o;
}

// ---------------------------------------------------------------------------
// Kernel 3: out = relu(concat(h[nodeset], agg) @ Ww.T + Wb).  M=20000 N=256 K=512.
// 64x128 tile (626 blocks, 2.4/CU), wave = 64x32 (mt=4, nt=2).
// ---------------------------------------------------------------------------
__global__ __launch_bounds__(256)
void fgemm(const float* __restrict__ h, const int* __restrict__ nodeset,
           const unsigned short* __restrict__ agg,
           const float* __restrict__ Ww, const float* __restrict__ Wb,
           float* __restrict__ out) {
    __shared__ unsigned short ldsA[64 * 72];
    __shared__ unsigned short ldsB[128 * 72];

    const int tid  = threadIdx.x;
    const int row0 = blockIdx.x * 64;
    const int n0   = blockIdx.y * 128;
    const int lane = tid & 63;
    const int wv   = tid >> 6;
    const int wc   = wv << 5;              // 32-col slice per wave
    const int fr   = lane & 15;
    const int fk   = (lane >> 4) << 3;

    floatx4 acc[4][2];
#pragma unroll
    for (int i = 0; i < 4; ++i)
#pragma unroll
        for (int j = 0; j < 2; ++j)
            acc[i][j] = (floatx4){0.f, 0.f, 0.f, 0.f};

    for (int kb = 0; kb < 8; ++kb) {       // K = 512, BK = 64
        if (kb) __syncthreads();
        // A tile 64x64 (4096 elems), 4 float4/thread
#pragma unroll
        for (int i = 0; i < 4; ++i) {
            const int e = (i * 256 + tid) * 4;
            const int r = e >> 6;
            const int c = e & 63;
            const int gr = row0 + r;
            ushort4 s = {0, 0, 0, 0};
            if (gr < N_NODES) {
                if (kb < 4) {
                    const int src = nodeset[gr];
                    const float4 v = *(const float4*)(h + (size_t)src * IN_F + kb * 64 + c);
                    s.x = f2bf(v.x); s.y = f2bf(v.y); s.z = f2bf(v.z); s.w = f2bf(v.w);
                } else {
                    s = *(const ushort4*)(agg + (size_t)gr * HID_F + (kb - 4) * 64 + c);
                }
            }
            *(ushort4*)(&ldsA[r * 72 + c]) = s;
        }
        // B tile 128x64 (8192 elems), 8 float4/thread
#pragma unroll
        for (int i = 0; i < 8; ++i) {
            const int e = (i * 256 + tid) * 4;
            const int r = e >> 6;
            const int c = e & 63;
            const float4 wv4 = *(const float4*)(Ww + (size_t)(n0 + r) * KCAT + kb * 64 + c);
            ushort4 t;
            t.x = f2bf(wv4.x); t.y = f2bf(wv4.y); t.z = f2bf(wv4.z); t.w = f2bf(wv4.w);
            *(ushort4*)(&ldsB[r * 72 + c]) = t;
        }
        __syncthreads();
#pragma unroll
        for (int ks = 0; ks < 2; ++ks) {
            bf16x8 av[4], bv[2];
#pragma unroll
            for (int mt = 0; mt < 4; ++mt)
                av[mt] = *reinterpret_cast<const bf16x8*>(&ldsA[(mt * 16 + fr) * 72 + ks * 32 + fk]);
#pragma unroll
            for (int nt = 0; nt < 2; ++nt)
                bv[nt] = *reinterpret_cast<const bf16x8*>(&ldsB[(wc + nt * 16 + fr) * 72 + ks * 32 + fk]);
#pragma unroll
            for (int mt = 0; mt < 4; ++mt)
#pragma unroll
                for (int nt = 0; nt < 2; ++nt)
                    acc[mt][nt] = __builtin_amdgcn_mfma_f32_16x16x32_bf16(av[mt], bv[nt], acc[mt][nt], 0, 0, 0);
        }
    }

    const int erow = (lane >> 4) << 2;
    const int ecol = lane & 15;
#pragma unroll
    for (int nt = 0; nt < 2; ++nt) {
        const int gcol = n0 + wc + nt * 16 + ecol;
        const float bias = Wb[gcol];
#pragma unroll
        for (int mt = 0; mt < 4; ++mt)
#pragma unroll
            for (int r = 0; r < 4; ++r) {
                const int gr = row0 + mt * 16 + erow + r;
                if (gr < N_NODES) {
                    const float v = acc[mt][nt][r] + bias;
                    out[(size_t)gr * OUT_F + gcol] = (v > 0.f ? v : 0.f);
                }
            }
    }
}

// ---------------------------------------------------------------------------
// Kernel 4: in-place row L2 normalize. One wave per row.
// ---------------------------------------------------------------------------
__global__ __launch_bounds__(256)
void normk(float* __restrict__ out) {
    const int row = blockIdx.x * 4 + (threadIdx.x >> 6);
    const int lane = threadIdx.x & 63;
    float4 v = *(float4*)(out + (size_t)row * OUT_F + lane * 4);
    float ss = v.x * v.x + v.y * v.y + v.z * v.z + v.w * v.w;
#pragma unroll
    for (int off = 32; off > 0; off >>= 1)
        ss += __shfl_xor(ss, off, 64);
    const float s = rsqrtf(ss);
    v.x *= s; v.y *= s; v.z *= s; v.w *= s;
    *(float4*)(out + (size_t)row * OUT_F + lane * 4) = v;
}

extern "C" void kernel_launch(void* const* d_in, const int* in_sizes, int n_in,
                              void* d_out, int out_size, void* d_ws, size_t ws_size,
                              hipStream_t stream) {
    const float* h        = (const float*)d_in[0];
    const int*   nodeset  = (const int*)d_in[1];
    const int*   nb_nodes = (const int*)d_in[2];
    const float* nb_w     = (const float*)d_in[3];
    const float* Qw       = (const float*)d_in[4];
    const float* Qb       = (const float*)d_in[5];
    const float* Ww       = (const float*)d_in[6];
    const float* Wb       = (const float*)d_in[7];
    float* out = (float*)d_out;

    unsigned short* q   = (unsigned short*)d_ws;
    unsigned short* agg = q + (size_t)M_TOTAL * HID_F;

    qgemm<<<dim3((M_TOTAL + 127) / 128, 2), 256, 0, stream>>>(h, Qw, Qb, q);
    aggk <<<dim3(N_NODES / 4),             256, 0, stream>>>(q, nb_nodes, nb_w, agg);
    fgemm<<<dim3((N_NODES + 63) / 64, 2),  256, 0, stream>>>(h, nodeset, agg, Ww, Wb, out);
    normk<<<dim3(N_NODES / 4),             256, 0, stream>>>(out);
}

// Round 3
// 259.053 us; speedup vs baseline: 1.4301x; 1.2052x over previous
//
#include <hip/hip_runtime.h>
#include <hip/hip_bf16.h>

// PinSageConv on MI355X — round 3.
// q[v] = relu(h[v] @ Q_w.T + Q_b) precomputed for all 100k nodes, stored FP8
// e4m3 (OCP, HW cvt): halves the 1M-row random-gather traffic and fits q in
// aggregate L2 (25.6 MB). Weights pre-converted to bf16 once (wcvt) so GEMM
// staging is pure global_load_lds (no VALU cvt on the B path).
// Workspace layout (46.5 MB < 61.4 MB provided):
//   q_fp8 [100000][256] u8   @ 0           (25,600,000)
//   aggF  [ 20000][256] f32  @ 25,600,000  (20,480,000)
//   QwB   [256][256]    bf16 @ 46,080,000  (   131,072)
//   WwB   [256][512]    bf16 @ 46,211,072  (   262,144)

#define M_TOTAL 100000
#define N_NODES 20000
#define T_NB    50
#define IN_F    256
#define HID_F   256
#define OUT_F   256
#define KCAT    512

typedef __bf16 bf16x8 __attribute__((ext_vector_type(8)));
typedef float  floatx4 __attribute__((ext_vector_type(4)));
typedef float  v2f     __attribute__((ext_vector_type(2)));

__device__ __forceinline__ unsigned short f2bf(float f) {
    unsigned int u = __float_as_uint(f);
    u += 0x7fffu + ((u >> 16) & 1u);          // RTNE
    return (unsigned short)(u >> 16);
}
__device__ __forceinline__ unsigned char f2fp8(float v) {
    return (unsigned char)(__builtin_amdgcn_cvt_pk_fp8_f32(v, 0.f, 0, false) & 0xff);
}
__device__ __forceinline__ void gload16(const void* g, void* l) {
    __builtin_amdgcn_global_load_lds(
        (const __attribute__((address_space(1))) unsigned int*)g,
        (__attribute__((address_space(3))) unsigned int*)l, 16, 0, 0);
}
__device__ __forceinline__ bf16x8 cvt_frag(float4 a, float4 b) {
    bf16x8 r;
    r[0] = (__bf16)a.x; r[1] = (__bf16)a.y; r[2] = (__bf16)a.z; r[3] = (__bf16)a.w;
    r[4] = (__bf16)b.x; r[5] = (__bf16)b.y; r[6] = (__bf16)b.z; r[7] = (__bf16)b.w;
    return r;
}

// ---------------------------------------------------------------------------
// Kernel 0: convert Qw (65536 f32) and Ww (131072 f32) to bf16. 4 elems/thread.
// ---------------------------------------------------------------------------
__global__ __launch_bounds__(256)
void wcvt(const float* __restrict__ Qw, const float* __restrict__ Ww,
          unsigned short* __restrict__ QwB, unsigned short* __restrict__ WwB) {
    const int e = (blockIdx.x * 256 + threadIdx.x) * 4;
    float4 v;
    unsigned short* dst;
    if (e < 65536) { v = *(const float4*)(Qw + e);         dst = QwB + e; }
    else           { v = *(const float4*)(Ww + (e - 65536)); dst = WwB + (e - 65536); }
    ushort4 s;
    s.x = f2bf(v.x); s.y = f2bf(v.y); s.z = f2bf(v.z); s.w = f2bf(v.w);
    *(ushort4*)dst = s;
}

// ---------------------------------------------------------------------------
// Kernel 1: q = fp8(relu(h @ Qw.T + Qb)).  M=100000 N=256(full) K=256, BK=32.
// 64x256 tile, 4 waves (each 64x64). A fp32 async-staged (swizzle c^(row&7)),
// B bf16 async-staged (swizzle c^((row>>1)&3)). fp8 epilogue via LDS.
// ---------------------------------------------------------------------------
__global__ __launch_bounds__(256, 4)
void qgemm(const float* __restrict__ h, const unsigned short* __restrict__ QwB,
           const float* __restrict__ Qb, unsigned char* __restrict__ q) {
    __shared__ char smem[24576];               // A f32 8K | B bf16 16K; epi: C fp8 16K
    float* ldsA = (float*)smem;                // 64 rows x 8 chunks(16B)
    unsigned short* ldsB = (unsigned short*)(smem + 8192);   // 256 rows x 4 chunks
    unsigned char* ldsC = (unsigned char*)smem;              // 64 x 256 fp8

    const int tid  = threadIdx.x;
    const int row0 = blockIdx.x * 64;
    const int lane = tid & 63;
    const int wv   = tid >> 6;
    const int wc   = wv << 6;              // wave's 64-col slice
    const int fr   = lane & 15;
    const int fk   = (lane >> 4) << 3;     // {0,8,16,24}
    const int ca   = fk >> 2;              // A chunk base {0,2,4,6}
    const int cb   = fk >> 3;              // B chunk {0,1,2,3}

    floatx4 acc[4][4];
#pragma unroll
    for (int i = 0; i < 4; ++i)
#pragma unroll
        for (int j = 0; j < 4; ++j)
            acc[i][j] = (floatx4){0.f, 0.f, 0.f, 0.f};

    for (int kb = 0; kb < 8; ++kb) {       // K=256, BK=32
        if (kb) __syncthreads();
        const int k0 = kb * 32;
        // A: 64x32 f32 = 512 chunks
#pragma unroll
        for (int i = 0; i < 2; ++i) {
            const int L   = tid + i * 256;
            const int row = L >> 3;
            const int cg  = (L & 7) ^ (row & 7);
            const int gr  = min(row0 + row, M_TOTAL - 1);
            gload16(h + (size_t)gr * IN_F + k0 + cg * 4, smem + L * 16);
        }
        // B: 256x32 bf16 = 1024 chunks
#pragma unroll
        for (int i = 0; i < 4; ++i) {
            const int L   = tid + i * 256;
            const int row = L >> 2;
            const int cg  = (L & 3) ^ ((row >> 1) & 3);
            gload16(QwB + (size_t)row * IN_F + k0 + cg * 8, smem + 8192 + L * 16);
        }
        __syncthreads();

        bf16x8 av[4], bv[4];
#pragma unroll
        for (int mt = 0; mt < 4; ++mt) {
            const int row = mt * 16 + fr;
            const int sw  = row & 7;
            const float4 p0 = *(const float4*)(ldsA + (row * 8 + (ca ^ sw)) * 4);
            const float4 p1 = *(const float4*)(ldsA + (row * 8 + ((ca + 1) ^ sw)) * 4);
            av[mt] = cvt_frag(p0, p1);
        }
#pragma unroll
        for (int nt = 0; nt < 4; ++nt) {
            const int row = wc + nt * 16 + fr;
            const int sw  = (row >> 1) & 3;
            bv[nt] = *reinterpret_cast<const bf16x8*>(ldsB + row * 32 + (cb ^ sw) * 8);
        }
#pragma unroll
        for (int mt = 0; mt < 4; ++mt)
#pragma unroll
            for (int nt = 0; nt < 4; ++nt)
                acc[mt][nt] = __builtin_amdgcn_mfma_f32_16x16x32_bf16(av[mt], bv[nt], acc[mt][nt], 0, 0, 0);
    }

    // Epilogue: bias+relu -> fp8 tile in LDS -> coalesced 16B stores.
    __syncthreads();
    const int erow = (lane >> 4) << 2;
    const int ecol = lane & 15;
#pragma unroll
    for (int nt = 0; nt < 4; ++nt) {
        const int cl = wc + nt * 16 + ecol;
        const float bias = Qb[cl];
#pragma unroll
        for (int mt = 0; mt < 4; ++mt)
#pragma unroll
            for (int r = 0; r < 4; ++r) {
                const int rl = mt * 16 + erow + r;
                const float v = acc[mt][nt][r] + bias;
                ldsC[rl * 256 + cl] = f2fp8(v > 0.f ? v : 0.f);
            }
    }
    __syncthreads();
#pragma unroll
    for (int i = 0; i < 4; ++i) {          // 64 rows x 16 chunks = 1024
        const int L   = tid + i * 256;
        const int row = L >> 4;
        const int c   = L & 15;
        const int gr  = row0 + row;
        if (gr < M_TOTAL)
            *(uint4*)(q + (size_t)gr * HID_F + c * 16) = *(const uint4*)(ldsC + row * 256 + c * 16);
    }
}

// ---------------------------------------------------------------------------
// Kernel 2: aggF[n] = sum_t w[n,t]*q[nb[n,t]] / sum_t w[n,t]  (fp32 out).
// One wave/node; 2 neighbors per load instruction (half-wave each, 8B/lane).
// ---------------------------------------------------------------------------
__global__ __launch_bounds__(256)
void aggk(const unsigned char* __restrict__ q, const int* __restrict__ nb,
          const float* __restrict__ w, float* __restrict__ aggF) {
    const int node = blockIdx.x * 4 + (threadIdx.x >> 6);
    const int lane = threadIdx.x & 63;

    int   idx_l = 0;
    float w_l   = 0.f;
    if (lane < T_NB) {
        idx_l = nb[(size_t)node * T_NB + lane];
        w_l   = w[(size_t)node * T_NB + lane];
    }
    float sw = w_l;
#pragma unroll
    for (int off = 32; off > 0; off >>= 1)
        sw += __shfl_xor(sw, off, 64);

    const int half = lane >> 5;            // lanes 0-31: even t, 32-63: odd t
    const int foff = (lane & 31) * 8;      // 8 features per lane
    float a[8];
#pragma unroll
    for (int j = 0; j < 8; ++j) a[j] = 0.f;

#pragma unroll
    for (int i = 0; i < T_NB / 2; ++i) {
        const int   t   = 2 * i + half;
        const int   idx = __shfl(idx_l, t, 64);
        const float wt  = __shfl(w_l, t, 64);
        const uint2 u   = *(const uint2*)(q + (size_t)idx * HID_F + foff);
        v2f p;
        p = __builtin_amdgcn_cvt_pk_f32_fp8(u.x, false); a[0] += wt * p[0]; a[1] += wt * p[1];
        p = __builtin_amdgcn_cvt_pk_f32_fp8(u.x, true);  a[2] += wt * p[0]; a[3] += wt * p[1];
        p = __builtin_amdgcn_cvt_pk_f32_fp8(u.y, false); a[4] += wt * p[0]; a[5] += wt * p[1];
        p = __builtin_amdgcn_cvt_pk_f32_fp8(u.y, true);  a[6] += wt * p[0]; a[7] += wt * p[1];
    }
#pragma unroll
    for (int j = 0; j < 8; ++j) a[j] += __shfl_xor(a[j], 32, 64);

    if (lane < 32) {
        const float inv = 1.0f / sw;
        float4 o0 = make_float4(a[0] * inv, a[1] * inv, a[2] * inv, a[3] * inv);
        float4 o1 = make_float4(a[4] * inv, a[5] * inv, a[6] * inv, a[7] * inv);
        *(float4*)(aggF + (size_t)node * HID_F + foff)     = o0;
        *(float4*)(aggF + (size_t)node * HID_F + foff + 4) = o1;
    }
}

// ---------------------------------------------------------------------------
// Kernel 3: out = relu(concat(h[nodeset], aggF) @ Ww.T + Wb).  M=20000 N=256 K=512.
// 64x128 tile, BK=64. A fp32 async-gathered (h rows kb<4, aggF rows kb>=4,
// swizzle c^(row&15)); B bf16 async (swizzle c^(row&7)). Wave = 64x32.
// ---------------------------------------------------------------------------
__global__ __launch_bounds__(256)
void fgemm(const float* __restrict__ h, const int* __restrict__ nodeset,
           const float* __restrict__ aggF, const unsigned short* __restrict__ WwB,
           const float* __restrict__ Wb, float* __restrict__ out) {
    __shared__ char smem[32768];
    float* ldsA = (float*)smem;                              // 64 rows x 16 chunks
    unsigned short* ldsB = (unsigned short*)(smem + 16384);  // 128 rows x 8 chunks

    const int tid  = threadIdx.x;
    const int row0 = blockIdx.x * 64;
    const int n0   = blockIdx.y * 128;
    const int lane = tid & 63;
    const int wv   = tid >> 6;
    const int wc   = wv << 5;              // 32-col slice per wave
    const int fr   = lane & 15;
    const int fk   = (lane >> 4) << 3;
    const int ca   = fk >> 2;              // {0,2,4,6}
    const int cbB  = fk >> 3;              // {0,1,2,3}

    int nsrow[4];
#pragma unroll
    for (int i = 0; i < 4; ++i) {
        const int row = (tid + i * 256) >> 4;
        nsrow[i] = nodeset[min(row0 + row, N_NODES - 1)];
    }

    floatx4 acc[4][2];
#pragma unroll
    for (int i = 0; i < 4; ++i)
#pragma unroll
        for (int j = 0; j < 2; ++j)
            acc[i][j] = (floatx4){0.f, 0.f, 0.f, 0.f};

    for (int kb = 0; kb < 8; ++kb) {       // K=512, BK=64
        if (kb) __syncthreads();
        // A: 64x64 f32 = 1024 chunks
#pragma unroll
        for (int i = 0; i < 4; ++i) {
            const int L   = tid + i * 256;
            const int row = L >> 4;
            const int cg  = (L & 15) ^ (row & 15);
            const float* src = (kb < 4)
                ? h    + (size_t)nsrow[i] * IN_F + kb * 64 + cg * 4
                : aggF + (size_t)min(row0 + row, N_NODES - 1) * HID_F + (kb - 4) * 64 + cg * 4;
            gload16(src, smem + L * 16);
        }
        // B: 128x64 bf16 = 1024 chunks
#pragma unroll
        for (int i = 0; i < 4; ++i) {
            const int L   = tid + i * 256;
            const int row = L >> 3;
            const int cg  = (L & 7) ^ (row & 7);
            gload16(WwB + (size_t)(n0 + row) * KCAT + kb * 64 + cg * 8, smem + 16384 + L * 16);
        }
        __syncthreads();

#pragma unroll
        for (int ks = 0; ks < 2; ++ks) {
            bf16x8 av[4], bv[2];
#pragma unroll
            for (int mt = 0; mt < 4; ++mt) {
                const int row = mt * 16 + fr;
                const int sw  = row & 15;
                const int c0  = ks * 8 + ca;
                const float4 p0 = *(const float4*)(ldsA + (row * 16 + (c0 ^ sw)) * 4);
                const float4 p1 = *(const float4*)(ldsA + (row * 16 + ((c0 + 1) ^ sw)) * 4);
                av[mt] = cvt_frag(p0, p1);
            }
#pragma unroll
            for (int nt = 0; nt < 2; ++nt) {
                const int row = wc + nt * 16 + fr;
                const int sw  = row & 7;
                bv[nt] = *reinterpret_cast<const bf16x8*>(ldsB + row * 64 + ((ks * 4 + cbB) ^ sw) * 8);
            }
#pragma unroll
            for (int mt = 0; mt < 4; ++mt)
#pragma unroll
                for (int nt = 0; nt < 2; ++nt)
                    acc[mt][nt] = __builtin_amdgcn_mfma_f32_16x16x32_bf16(av[mt], bv[nt], acc[mt][nt], 0, 0, 0);
        }
    }

    const int erow = (lane >> 4) << 2;
    const int ecol = lane & 15;
#pragma unroll
    for (int nt = 0; nt < 2; ++nt) {
        const int gcol = n0 + wc + nt * 16 + ecol;
        const float bias = Wb[gcol];
#pragma unroll
        for (int mt = 0; mt < 4; ++mt)
#pragma unroll
            for (int r = 0; r < 4; ++r) {
                const int gr = row0 + mt * 16 + erow + r;
                if (gr < N_NODES) {
                    const float v = acc[mt][nt][r] + bias;
                    out[(size_t)gr * OUT_F + gcol] = (v > 0.f ? v : 0.f);
                }
            }
    }
}

// ---------------------------------------------------------------------------
// Kernel 4: in-place row L2 normalize. One wave per row.
// ---------------------------------------------------------------------------
__global__ __launch_bounds__(256)
void normk(float* __restrict__ out) {
    const int row = blockIdx.x * 4 + (threadIdx.x >> 6);
    const int lane = threadIdx.x & 63;
    float4 v = *(float4*)(out + (size_t)row * OUT_F + lane * 4);
    float ss = v.x * v.x + v.y * v.y + v.z * v.z + v.w * v.w;
#pragma unroll
    for (int off = 32; off > 0; off >>= 1)
        ss += __shfl_xor(ss, off, 64);
    const float s = rsqrtf(ss);
    v.x *= s; v.y *= s; v.z *= s; v.w *= s;
    *(float4*)(out + (size_t)row * OUT_F + lane * 4) = v;
}

extern "C" void kernel_launch(void* const* d_in, const int* in_sizes, int n_in,
                              void* d_out, int out_size, void* d_ws, size_t ws_size,
                              hipStream_t stream) {
    const float* h        = (const float*)d_in[0];
    const int*   nodeset  = (const int*)d_in[1];
    const int*   nb_nodes = (const int*)d_in[2];
    const float* nb_w     = (const float*)d_in[3];
    const float* Qw       = (const float*)d_in[4];
    const float* Qb       = (const float*)d_in[5];
    const float* Ww       = (const float*)d_in[6];
    const float* Wb       = (const float*)d_in[7];
    float* out = (float*)d_out;

    unsigned char*  q    = (unsigned char*)d_ws;                          // 25.6 MB
    float*          aggF = (float*)((char*)d_ws + 25600000);              // 20.48 MB
    unsigned short* QwB  = (unsigned short*)((char*)d_ws + 46080000);     // 128 KB
    unsigned short* WwB  = (unsigned short*)((char*)d_ws + 46211072);     // 256 KB

    wcvt <<<dim3(192),                     256, 0, stream>>>(Qw, Ww, QwB, WwB);
    qgemm<<<dim3((M_TOTAL + 63) / 64),     256, 0, stream>>>(h, QwB, Qb, q);
    aggk <<<dim3(N_NODES / 4),             256, 0, stream>>>(q, nb_nodes, nb_w, aggF);
    fgemm<<<dim3((N_NODES + 63) / 64, 2),  256, 0, stream>>>(h, nodeset, aggF, WwB, Wb, out);
    normk<<<dim3(N_NODES / 4),             256, 0, stream>>>(out);
}